// Round 9
// baseline (112.272 us; speedup 1.0000x reference)
//
#include <hip/hip_runtime.h>

typedef __attribute__((ext_vector_type(8))) short short8v;
typedef __attribute__((ext_vector_type(4))) float f32x4;
typedef __attribute__((ext_vector_type(16))) float f32x16;
typedef unsigned short u16;
typedef unsigned int u32;

#define MFMA __builtin_amdgcn_mfma_f32_16x16x32_bf16
#define MFMA32 __builtin_amdgcn_mfma_f32_32x32x16_bf16

// ---------- helpers ----------
__device__ __forceinline__ u16 f2b(float f) {
  u32 u = __float_as_uint(f);
  u = (u + 0x7FFFu + ((u >> 16) & 1u)) >> 16;
  return (u16)u;
}
__device__ __forceinline__ void g2l16(const void* g, void* l) {
  __builtin_amdgcn_global_load_lds(
      (const __attribute__((address_space(1))) unsigned int*)g,
      (__attribute__((address_space(3))) unsigned int*)l, 16, 0, 0);
}

// sizes
#define N_TOK 2048
#define DIM 1024
#define NH 16
#define HD 64

// Q pre-scale: hd^-0.5 * log2(e)  (softmax runs in exp2 domain)
#define QSCALE 0.18033688011112042f

// workspace layout (bytes)
#define OFF_PERM 0
#define OFF_CNT 8192
#define OFF_WT 16384                        // 16 MB: [tensor][expert][1024][1024] bf16, WT[n][k]
#define OFF_Q (OFF_WT + 16777216)
#define OFF_K (OFF_Q + 4194304)
#define OFF_VT (OFF_K + 4194304)            // [16][64][2048] bf16
#define OFF_AT (OFF_VT + 4194304)
#define OFF_O (OFF_AT + 4194304)            // f32 [2048][1024]
#define OFF_O2 (OFF_O + 8388608)            // f32 [2048][1024] split-K partial

// ---------- fused: weight transpose-cast (z<8) + prep partition (z==8) ----------
__global__ __launch_bounds__(256) void wcast_prep(const float* __restrict__ wq,
                                                  const float* __restrict__ wk,
                                                  const float* __restrict__ wv,
                                                  const float* __restrict__ wo,
                                                  u16* __restrict__ wT,
                                                  const void* __restrict__ masks,
                                                  int* __restrict__ perm,
                                                  int* __restrict__ cnt) {
  __shared__ float t[32][33];
  __shared__ u32 red[256];
  __shared__ int scan[256];
  const int tx = threadIdx.x, ty = threadIdx.y;
  if (blockIdx.z == 8) {
    if (blockIdx.x != 0 || blockIdx.y != 0) return;
    const int tid = ty * 32 + tx;
    const u32* mw = (const u32*)masks;
    u32 mx = 0;
    for (int i = tid; i < 1024; i += 256) { u32 v = mw[i]; mx = mx > v ? mx : v; }
    red[tid] = mx;
    __syncthreads();
    for (int off = 128; off; off >>= 1) {
      if (tid < off) red[tid] = red[tid] > red[tid + off] ? red[tid] : red[tid + off];
      __syncthreads();
    }
    const bool isbyte = red[0] > 1u;
    int md[8];
    int c0loc = 0;
    #pragma unroll
    for (int j = 0; j < 8; ++j) {
      const int n = tid * 8 + j;
      int m1;
      if (isbyte) m1 = ((const unsigned char*)masks)[N_TOK + n] != 0;
      else        m1 = mw[N_TOK + n] != 0;
      md[j] = m1;
      c0loc += (m1 == 0);
    }
    scan[tid] = c0loc;
    __syncthreads();
    for (int off = 1; off < 256; off <<= 1) {
      int v = (tid >= off) ? scan[tid - off] : 0;
      __syncthreads();
      scan[tid] += v;
      __syncthreads();
    }
    const int incl = scan[tid];
    const int total0 = scan[255];
    const int excl0 = incl - c0loc;
    int p0 = excl0;
    int p1 = total0 + (tid * 8 - excl0);
    #pragma unroll
    for (int j = 0; j < 8; ++j) {
      const int n = tid * 8 + j;
      if (!md[j]) perm[p0++] = n; else perm[p1++] = n;
    }
    if (tid == 0) cnt[0] = total0;
    return;
  }
  const int mat = blockIdx.z;               // tensor*2 + expert
  const int tensor = mat >> 1, expert = mat & 1;
  const float* src = (tensor == 0) ? wq : (tensor == 1) ? wk : (tensor == 2) ? wv : wo;
  src += (size_t)expert * (1 << 20);
  u16* dst = wT + ((size_t)mat << 20);
  const int k0 = blockIdx.x * 32, n0 = blockIdx.y * 32;
  #pragma unroll
  for (int r = 0; r < 4; ++r)
    t[ty + 8 * r][tx] = src[(size_t)(k0 + ty + 8 * r) * DIM + n0 + tx];
  __syncthreads();
  // vectorized u32-pair stores: thread -> (row=n, 2 k-pairs)
  const int tid = ty * 32 + tx;
  const int row = tid >> 3, pr = tid & 7;
  u32* dst32 = (u32*)(dst + (size_t)(n0 + row) * DIM + k0);
  #pragma unroll
  for (int j = 0; j < 2; ++j) {
    const int kp = pr + j * 8;
    u32 val;
    asm("v_cvt_pk_bf16_f32 %0, %1, %2" : "=v"(val)
        : "v"(t[2 * kp][row]), "v"(t[2 * kp + 1][row]));
    dst32[kp] = val;
  }
}

// ---------- QKV GEMM: A reg-staged from f32 x via perm (gather fused), B g2l16.
// BK=64, T2 swizzle; z==2 writes V^T via LDS transpose epilogue. ----------
__global__ __launch_bounds__(256) void gemm_qkv(const float* __restrict__ x,
                                                const int* __restrict__ perm,
                                                const u16* __restrict__ WTall,
                                                float qscale,
                                                u16* __restrict__ oq,
                                                u16* __restrict__ ok,
                                                u16* __restrict__ vT,
                                                const int* __restrict__ cntp) {
  const int z = blockIdx.z;                  // 0=q 1=k 2=v
  const int e = blockIdx.y >> 4;
  const int mt = blockIdx.y & 15;
  const int c0 = cntp[0];
  const int lo = e ? c0 : 0;
  const int hi = e ? N_TOK : c0;
  const int rb = mt * 128;
  if (rb >= hi || rb + 128 <= lo) return;
  const int cb = blockIdx.x * 128;
  const u16* W = WTall + ((size_t)(z * 2 + e) << 20);
  const float scl = (z == 0) ? qscale : 1.f;

  const int tid = threadIdx.x;
  const int w = tid >> 6, l = tid & 63, lg = l >> 4, ln = l & 15;
  const int wm = (w >> 1) * 64, wn = (w & 1) * 64;

  __shared__ __align__(16) char smem[65536];   // 2 bufs x (A 16K + B 16K)

  // A staging: thread -> row (0..127), half (32 k each); gather via perm
  const int arow = tid >> 1, ahalf = tid & 1;
  const float* apx = x + (size_t)perm[rb + arow] * DIM + ahalf * 32;
  float4 af[8];
  auto loadA = [&](int it) {
    const float4* p = (const float4*)(apx + it * 64);
    #pragma unroll
    for (int j = 0; j < 8; ++j) af[j] = p[j];
  };
  auto writeA = [&](int b_) {
    #pragma unroll
    for (int j16 = 0; j16 < 4; ++j16) {
      u32 pk0, pk1, pk2, pk3;
      const float4 f0 = af[j16 * 2], f1 = af[j16 * 2 + 1];
      asm("v_cvt_pk_bf16_f32 %0, %1, %2" : "=v"(pk0) : "v"(f0.x), "v"(f0.y));
      asm("v_cvt_pk_bf16_f32 %0, %1, %2" : "=v"(pk1) : "v"(f0.z), "v"(f0.w));
      asm("v_cvt_pk_bf16_f32 %0, %1, %2" : "=v"(pk2) : "v"(f1.x), "v"(f1.y));
      asm("v_cvt_pk_bf16_f32 %0, %1, %2" : "=v"(pk3) : "v"(f1.z), "v"(f1.w));
      *(uint4*)&smem[b_ * 32768 + arow * 128 +
                     ((ahalf * 64 + j16 * 16) ^ ((arow & 7) << 4))] =
          make_uint4(pk0, pk1, pk2, pk3);
    }
  };
  auto stageB = [&](int it, int b_) {
    #pragma unroll
    for (int c = 0; c < 4; ++c) {
      const int cc = tid + c * 256;            // 0..1023
      const int row = cc >> 3;
      const int colb = ((cc & 7) * 16) ^ ((row & 7) << 4);
      g2l16((const char*)W + (size_t)(cb + row) * 2048 + it * 128 + colb,
            &smem[b_ * 32768 + 16384 + cc * 16]);
    }
  };

  f32x4 acc[4][4];
  #pragma unroll
  for (int i = 0; i < 4; ++i)
    #pragma unroll
    for (int j = 0; j < 4; ++j) acc[i][j] = (f32x4){0.f, 0.f, 0.f, 0.f};

  const int aswz = (ln & 7) << 4;
  loadA(0);
  stageB(0, 0);
  writeA(0);
  __syncthreads();
  for (int ii = 0; ii < 16; ++ii) {
    const int b_ = ii & 1;
    if (ii < 15) { loadA(ii + 1); stageB(ii + 1, b_ ^ 1); }
    #pragma unroll
    for (int ks = 0; ks < 2; ++ks) {
      short8v a[4], bb[4];
      #pragma unroll
      for (int mi = 0; mi < 4; ++mi)
        a[mi] = *(const short8v*)&smem[b_ * 32768 + (wm + mi * 16 + ln) * 128 +
                                       ((ks * 64 + lg * 16) ^ aswz)];
      #pragma unroll
      for (int ni = 0; ni < 4; ++ni)
        bb[ni] = *(const short8v*)&smem[b_ * 32768 + 16384 + (wn + ni * 16 + ln) * 128 +
                                        ((ks * 64 + lg * 16) ^ aswz)];
      __builtin_amdgcn_s_setprio(1);
      #pragma unroll
      for (int mi = 0; mi < 4; ++mi)
        #pragma unroll
        for (int ni = 0; ni < 4; ++ni)
          acc[mi][ni] = MFMA(a[mi], bb[ni], acc[mi][ni], 0, 0, 0);
      __builtin_amdgcn_s_setprio(0);
    }
    if (ii < 15) writeA(b_ ^ 1);
    __syncthreads();
  }

  if (z < 2) {
    u16* OUT = z ? ok : oq;
    #pragma unroll
    for (int mi = 0; mi < 4; ++mi) {
      #pragma unroll
      for (int r = 0; r < 4; ++r) {
        const int row = rb + wm + mi * 16 + lg * 4 + r;
        if (row >= lo && row < hi) {
          #pragma unroll
          for (int ni = 0; ni < 4; ++ni)
            OUT[(size_t)row * DIM + cb + wn + ni * 16 + ln] = f2b(acc[mi][ni][r] * scl);
        }
      }
    }
  } else {
    // V^T epilogue: transpose acc [token][dim] -> vT[dim][token] via LDS.
    #pragma unroll
    for (int mi = 0; mi < 4; ++mi)
      #pragma unroll
      for (int ni = 0; ni < 4; ++ni) {
        const int dim = wn + ni * 16 + ln;
        const int tok = wm + mi * 16 + lg * 4;
        u32 p01, p23;
        asm("v_cvt_pk_bf16_f32 %0, %1, %2" : "=v"(p01) : "v"(acc[mi][ni][0]), "v"(acc[mi][ni][1]));
        asm("v_cvt_pk_bf16_f32 %0, %1, %2" : "=v"(p23) : "v"(acc[mi][ni][2]), "v"(acc[mi][ni][3]));
        *(uint2*)&smem[dim * 264 + tok * 2] = make_uint2(p01, p23);
      }
    __syncthreads();
    #pragma unroll 4
    for (int rr = 0; rr < 32; ++rr) {
      const int dim = w * 32 + rr;
      const u32 val = *(const u32*)&smem[dim * 264 + l * 4];
      const int tok = rb + 2 * l;
      u16* dst = vT + (size_t)(cb + dim) * 2048 + tok;
      if (tok >= lo && tok + 2 <= hi) {
        *(u32*)dst = val;
      } else {
        if (tok >= lo && tok < hi) dst[0] = (u16)(val & 0xFFFFu);
        if (tok + 1 >= lo && tok + 1 < hi) dst[1] = (u16)(val >> 16);
      }
    }
  }
}

// ---------- out-proj GEMM: 128x64 tile, BK=64, split-K2, f32 partials ----------
__global__ __launch_bounds__(256) void gemm_out(const u16* __restrict__ X,
                                                const u16* __restrict__ WTall,
                                                float* __restrict__ o0,
                                                float* __restrict__ o1,
                                                const int* __restrict__ cntp) {
  const int z = blockIdx.z;                  // K-half
  const int e = blockIdx.y >> 4;
  const int mt = blockIdx.y & 15;
  const int c0 = cntp[0];
  const int lo = e ? c0 : 0;
  const int hi = e ? N_TOK : c0;
  const int rb = mt * 128;
  if (rb >= hi || rb + 128 <= lo) return;
  const int cb = blockIdx.x * 64;
  float* OUT = z ? o1 : o0;
  const u16* W = WTall + ((size_t)(6 + e) << 20);
  const int kstart = z * 8;

  const int tid = threadIdx.x;
  const int w = tid >> 6, l = tid & 63, lg = l >> 4, ln = l & 15;
  const int wm = w * 32;

  __shared__ __align__(16) char smem[49152];   // 2 bufs x (A 16K + B 8K)

  auto stage = [&](int it, int b_) {
    #pragma unroll
    for (int c = 0; c < 6; ++c) {
      const int j = tid + c * 256;             // 0..1535
      const int isB = j >= 1024;
      const int cc = isB ? (j - 1024) : j;
      const int row = cc >> 3;
      const int colb = ((cc & 7) * 16) ^ ((row & 7) << 4);
      const char* base = isB ? (const char*)W + (size_t)(cb + row) * 2048
                             : (const char*)X + (size_t)(rb + row) * 2048;
      g2l16(base + it * 128 + colb, &smem[b_ * 24576 + isB * 16384 + cc * 16]);
    }
  };

  f32x4 acc[2][4];
  #pragma unroll
  for (int i = 0; i < 2; ++i)
    #pragma unroll
    for (int j = 0; j < 4; ++j) acc[i][j] = (f32x4){0.f, 0.f, 0.f, 0.f};

  const int aswz = (ln & 7) << 4;
  stage(kstart, 0);
  __syncthreads();
  for (int ii = 0; ii < 8; ++ii) {
    const int b_ = ii & 1;
    if (ii < 7) stage(kstart + ii + 1, b_ ^ 1);
    #pragma unroll
    for (int ks = 0; ks < 2; ++ks) {
      short8v a[2], bb[4];
      #pragma unroll
      for (int mi = 0; mi < 2; ++mi)
        a[mi] = *(const short8v*)&smem[b_ * 24576 + (wm + mi * 16 + ln) * 128 +
                                       ((ks * 64 + lg * 16) ^ aswz)];
      #pragma unroll
      for (int ni = 0; ni < 4; ++ni)
        bb[ni] = *(const short8v*)&smem[b_ * 24576 + 16384 + (ni * 16 + ln) * 128 +
                                        ((ks * 64 + lg * 16) ^ aswz)];
      __builtin_amdgcn_s_setprio(1);
      #pragma unroll
      for (int mi = 0; mi < 2; ++mi)
        #pragma unroll
        for (int ni = 0; ni < 4; ++ni)
          acc[mi][ni] = MFMA(a[mi], bb[ni], acc[mi][ni], 0, 0, 0);
      __builtin_amdgcn_s_setprio(0);
    }
    __syncthreads();
  }

  #pragma unroll
  for (int mi = 0; mi < 2; ++mi) {
    #pragma unroll
    for (int r = 0; r < 4; ++r) {
      const int row = rb + wm + mi * 16 + lg * 4 + r;
      if (row >= lo && row < hi) {
        #pragma unroll
        for (int ni = 0; ni < 4; ++ni)
          OUT[(size_t)row * DIM + cb + ni * 16 + ln] = acc[mi][ni][r];
      }
    }
  }
}

// ---------- flash attention: barrier-free, wave-private K/V, depth-2 pipeline,
// single merged defer-max branch per iter (schedulable A/B interleave) ----------
__global__ __launch_bounds__(256, 2) void attn_fwd(const u16* __restrict__ qg,
                                                   const u16* __restrict__ kg,
                                                   const u16* __restrict__ vTg,
                                                   u16* __restrict__ og) {
  const int bid = blockIdx.x;
  const int wg = (bid & 7) * 64 + (bid >> 3);   // bijective XCD swizzle (512 = 8*64)
  const int qt = wg & 31, h = wg >> 5;
  const int tid = threadIdx.x, kq = tid >> 6, l = tid & 63;
  const int q31 = l & 31, hi = l >> 5;
  const int hi16 = hi * 16, hi4 = hi * 4;

  __shared__ __align__(16) char smem[67584];   // 4 waves x 16KB dbuf + 2KB merge
  const int base = kq * 16384;

  // per-lane staging source bases (inverse-swizzled so LDS writes are linear)
  const int lr3 = l >> 3, lc3 = l & 7;
  const char* baseK = (const char*)kg + (size_t)(kq * 512 + lr3) * 2048 + h * 128 +
                      ((lc3 << 4) ^ (lr3 << 4));
  const int cpr = lc3 ^ lr3;                  // swizzled col/16 for V
  const int dhalf = (cpr >> 2) & 1;
  const char* baseV = (const char*)vTg + (size_t)(h * 64 + lr3 + dhalf * 32) * 4096 +
                      kq * 1024 + ((cpr & 3) << 4);

  // Q fragments (B-operand), 2 sets of 32 q-cols
  const char* qb0 = (const char*)qg + (size_t)(qt * 64 + q31) * 2048 + h * 128;
  short8v qfA[4], qfB[4];
  #pragma unroll
  for (int t = 0; t < 4; ++t) {
    qfA[t] = *(const short8v*)(qb0 + t * 32 + hi16);
    qfB[t] = *(const short8v*)(qb0 + 65536 + t * 32 + hi16);
  }

  uint4 rk0, rk1, rk2, rk3, rv0, rv1, rv2, rv3;
  auto loadKV = [&](int it) {
    const char* pk = baseK + (size_t)it * 65536;   // 32 key-rows x 2048B
    rk0 = *(const uint4*)(pk);
    rk1 = *(const uint4*)(pk + 16384);
    rk2 = *(const uint4*)(pk + 32768);
    rk3 = *(const uint4*)(pk + 49152);
    const char* pv = baseV + it * 64;              // 32 keys x 2B
    rv0 = *(const uint4*)(pv);
    rv1 = *(const uint4*)(pv + 32768);
    rv2 = *(const uint4*)(pv + 65536);
    rv3 = *(const uint4*)(pv + 98304);
  };
  auto writeK = [&](int b_) {
    const int Kb = base + b_ * 8192;
    *(uint4*)&smem[Kb + 0 + l * 16] = rk0;
    *(uint4*)&smem[Kb + 1024 + l * 16] = rk1;
    *(uint4*)&smem[Kb + 2048 + l * 16] = rk2;
    *(uint4*)&smem[Kb + 3072 + l * 16] = rk3;
  };
  auto writeV = [&](int b_) {
    const int Vb = base + b_ * 8192 + 4096;
    *(uint4*)&smem[Vb + 0 + l * 16] = rv0;
    *(uint4*)&smem[Vb + 1024 + l * 16] = rv1;
    *(uint4*)&smem[Vb + 2048 + l * 16] = rv2;
    *(uint4*)&smem[Vb + 3072 + l * 16] = rv3;
  };

  float mA = -1e30f, lA = 0.f, mB = -1e30f, lB = 0.f;
  f32x16 accA0, accA1, accB0, accB1;
  #pragma unroll
  for (int r = 0; r < 16; ++r) { accA0[r] = 0.f; accA1[r] = 0.f; accB0[r] = 0.f; accB1[r] = 0.f; }

  struct PA { short8v p0, p1; };

  // paired softmax: single merged rescale branch -> big schedulable block
  auto softmax_pair = [&](f32x16& sA_, f32x16& sB_, PA& oA, PA& oB) {
    float tA0 = fmaxf(fmaxf(sA_[0], sA_[1]), fmaxf(sA_[2], sA_[3]));
    float tB0 = fmaxf(fmaxf(sB_[0], sB_[1]), fmaxf(sB_[2], sB_[3]));
    float tA1 = fmaxf(fmaxf(sA_[4], sA_[5]), fmaxf(sA_[6], sA_[7]));
    float tB1 = fmaxf(fmaxf(sB_[4], sB_[5]), fmaxf(sB_[6], sB_[7]));
    float tA2 = fmaxf(fmaxf(sA_[8], sA_[9]), fmaxf(sA_[10], sA_[11]));
    float tB2 = fmaxf(fmaxf(sB_[8], sB_[9]), fmaxf(sB_[10], sB_[11]));
    float tA3 = fmaxf(fmaxf(sA_[12], sA_[13]), fmaxf(sA_[14], sA_[15]));
    float tB3 = fmaxf(fmaxf(sB_[12], sB_[13]), fmaxf(sB_[14], sB_[15]));
    float tmA = fmaxf(fmaxf(tA0, tA1), fmaxf(tA2, tA3));
    float tmB = fmaxf(fmaxf(tB0, tB1), fmaxf(tB2, tB3));
    tmA = fmaxf(tmA, __shfl_xor(tmA, 32, 64));
    tmB = fmaxf(tmB, __shfl_xor(tmB, 32, 64));
    const bool okb = (tmA <= mA + 11.0f) && (tmB <= mB + 11.0f);
    if (!__all(okb)) {                         // T13 defer-max, merged
      const float mnA = fmaxf(mA, tmA), mnB = fmaxf(mB, tmB);
      const float alA = __builtin_amdgcn_exp2f(mA - mnA);
      const float alB = __builtin_amdgcn_exp2f(mB - mnB);
      mA = mnA; mB = mnB; lA *= alA; lB *= alB;
      #pragma unroll
      for (int r = 0; r < 16; ++r) {
        const int qr = (r & 3) + 8 * (r >> 2) + hi4;
        const float arA = __shfl(alA, qr, 64);
        const float arB = __shfl(alB, qr, 64);
        accA0[r] *= arA; accA1[r] *= arA;
        accB0[r] *= arB; accB1[r] *= arB;
      }
    }
    float pA_[16], pB_[16];
    #pragma unroll
    for (int r = 0; r < 16; ++r) {
      pA_[r] = __builtin_amdgcn_exp2f(sA_[r] - mA);
      pB_[r] = __builtin_amdgcn_exp2f(sB_[r] - mB);
    }
    float rsA = ((pA_[0] + pA_[1]) + (pA_[2] + pA_[3])) + ((pA_[4] + pA_[5]) + (pA_[6] + pA_[7])) +
                (((pA_[8] + pA_[9]) + (pA_[10] + pA_[11])) + ((pA_[12] + pA_[13]) + (pA_[14] + pA_[15])));
    float rsB = ((pB_[0] + pB_[1]) + (pB_[2] + pB_[3])) + ((pB_[4] + pB_[5]) + (pB_[6] + pB_[7])) +
                (((pB_[8] + pB_[9]) + (pB_[10] + pB_[11])) + ((pB_[12] + pB_[13]) + (pB_[14] + pB_[15])));
    rsA += __shfl_xor(rsA, 32, 64);
    rsB += __shfl_xor(rsB, 32, 64);
    lA += rsA;
    lB += rsB;
    u32 a0, a1, a2, a3, a4, a5, a6, a7, b0, b1, b2, b3, b4, b5, b6, b7;
    asm("v_cvt_pk_bf16_f32 %0, %1, %2" : "=v"(a0) : "v"(pA_[0]), "v"(pA_[1]));
    asm("v_cvt_pk_bf16_f32 %0, %1, %2" : "=v"(a1) : "v"(pA_[2]), "v"(pA_[3]));
    asm("v_cvt_pk_bf16_f32 %0, %1, %2" : "=v"(a2) : "v"(pA_[4]), "v"(pA_[5]));
    asm("v_cvt_pk_bf16_f32 %0, %1, %2" : "=v"(a3) : "v"(pA_[6]), "v"(pA_[7]));
    asm("v_cvt_pk_bf16_f32 %0, %1, %2" : "=v"(a4) : "v"(pA_[8]), "v"(pA_[9]));
    asm("v_cvt_pk_bf16_f32 %0, %1, %2" : "=v"(a5) : "v"(pA_[10]), "v"(pA_[11]));
    asm("v_cvt_pk_bf16_f32 %0, %1, %2" : "=v"(a6) : "v"(pA_[12]), "v"(pA_[13]));
    asm("v_cvt_pk_bf16_f32 %0, %1, %2" : "=v"(a7) : "v"(pA_[14]), "v"(pA_[15]));
    asm("v_cvt_pk_bf16_f32 %0, %1, %2" : "=v"(b0) : "v"(pB_[0]), "v"(pB_[1]));
    asm("v_cvt_pk_bf16_f32 %0, %1, %2" : "=v"(b1) : "v"(pB_[2]), "v"(pB_[3]));
    asm("v_cvt_pk_bf16_f32 %0, %1, %2" : "=v"(b2) : "v"(pB_[4]), "v"(pB_[5]));
    asm("v_cvt_pk_bf16_f32 %0, %1, %2" : "=v"(b3) : "v"(pB_[6]), "v"(pB_[7]));
    asm("v_cvt_pk_bf16_f32 %0, %1, %2" : "=v"(b4) : "v"(pB_[8]), "v"(pB_[9]));
    asm("v_cvt_pk_bf16_f32 %0, %1, %2" : "=v"(b5) : "v"(pB_[10]), "v"(pB_[11]));
    asm("v_cvt_pk_bf16_f32 %0, %1, %2" : "=v"(b6) : "v"(pB_[12]), "v"(pB_[13]));
    asm("v_cvt_pk_bf16_f32 %0, %1, %2" : "=v"(b7) : "v"(pB_[14]), "v"(pB_[15]));
    asm volatile("v_permlane32_swap_b32 %0, %1" : "+v"(a0), "+v"(a2));
    asm volatile("v_permlane32_swap_b32 %0, %1" : "+v"(a1), "+v"(a3));
    asm volatile("v_permlane32_swap_b32 %0, %1" : "+v"(a4), "+v"(a6));
    asm volatile("v_permlane32_swap_b32 %0, %1" : "+v"(a5), "+v"(a7));
    asm volatile("v_permlane32_swap_b32 %0, %1" : "+v"(b0), "+v"(b2));
    asm volatile("v_permlane32_swap_b32 %0, %1" : "+v"(b1), "+v"(b3));
    asm volatile("v_permlane32_swap_b32 %0, %1" : "+v"(b4), "+v"(b6));
    asm volatile("v_permlane32_swap_b32 %0, %1" : "+v"(b5), "+v"(b7));
    union { u32 u[4]; short8v s; } uA0, uA1, uB0, uB1;
    uA0.u[0] = a0; uA0.u[1] = a1; uA0.u[2] = a2; uA0.u[3] = a3;
    uA1.u[0] = a4; uA1.u[1] = a5; uA1.u[2] = a6; uA1.u[3] = a7;
    uB0.u[0] = b0; uB0.u[1] = b1; uB0.u[2] = b2; uB0.u[3] = b3;
    uB1.u[0] = b4; uB1.u[1] = b5; uB1.u[2] = b6; uB1.u[3] = b7;
    oA.p0 = uA0.s; oA.p1 = uA1.s;
    oB.p0 = uB0.s; oB.p1 = uB1.s;
  };

  const int kswz = (q31 & 7) << 4;
  loadKV(0);
  writeK(0);
  writeV(0);
  loadKV(1);

  #pragma unroll 1
  for (int it = 0; it < 16; ++it) {
    const int cur = it & 1, nxt = cur ^ 1;
    const int Kb = base + cur * 8192, Vb = Kb + 4096;
    short8v kf0 = *(const short8v*)&smem[Kb + q31 * 128 + ((0 + hi16) ^ kswz)];
    short8v kf1 = *(const short8v*)&smem[Kb + q31 * 128 + ((32 + hi16) ^ kswz)];
    short8v kf2 = *(const short8v*)&smem[Kb + q31 * 128 + ((64 + hi16) ^ kswz)];
    short8v kf3 = *(const short8v*)&smem[Kb + q31 * 128 + ((96 + hi16) ^ kswz)];
    f32x16 sA, sB;
    #pragma unroll
    for (int r = 0; r < 16; ++r) { sA[r] = 0.f; sB[r] = 0.f; }
    __builtin_amdgcn_s_setprio(1);
    sA = MFMA32(kf0, qfA[0], sA, 0, 0, 0);
    sB = MFMA32(kf0, qfB[0], sB, 0, 0, 0);
    sA = MFMA32(kf1, qfA[1], sA, 0, 0, 0);
    sB = MFMA32(kf1, qfB[1], sB, 0, 0, 0);
    sA = MFMA32(kf2, qfA[2], sA, 0, 0, 0);
    sB = MFMA32(kf2, qfB[2], sB, 0, 0, 0);
    sA = MFMA32(kf3, qfA[3], sA, 0, 0, 0);
    sB = MFMA32(kf3, qfB[3], sB, 0, 0, 0);
    __builtin_amdgcn_s_setprio(0);
    if (it < 15) writeK(nxt);                 // loads aged ~0.6 iter

    PA pA, pB;
    softmax_pair(sA, sB, pA, pB);

    short8v vf00 = *(const short8v*)&smem[Vb + q31 * 128 + ((0 + hi16) ^ kswz)];
    short8v vf01 = *(const short8v*)&smem[Vb + q31 * 128 + ((64 + hi16) ^ kswz)];
    short8v vf10 = *(const short8v*)&smem[Vb + q31 * 128 + ((32 + hi16) ^ kswz)];
    short8v vf11 = *(const short8v*)&smem[Vb + q31 * 128 + ((96 + hi16) ^ kswz)];
    __builtin_amdgcn_s_setprio(1);
    accA0 = MFMA32(pA.p0, vf00, accA0, 0, 0, 0);
    accA1 = MFMA32(pA.p0, vf01, accA1, 0, 0, 0);
    accB0 = MFMA32(pB.p0, vf00, accB0, 0, 0, 0);
    accB1 = MFMA32(pB.p0, vf01, accB1, 0, 0, 0);
    accA0 = MFMA32(pA.p1, vf10, accA0, 0, 0, 0);
    accA1 = MFMA32(pA.p1, vf11, accA1, 0, 0, 0);
    accB0 = MFMA32(pB.p1, vf10, accB0, 0, 0, 0);
    accB1 = MFMA32(pB.p1, vf11, accB1, 0, 0, 0);
    __builtin_amdgcn_s_setprio(0);
    if (it < 15) writeV(nxt);
    if (it < 14) loadKV(it + 2);
  }
  __syncthreads();

  // ---- 4-way split-K merge (staging LDS dead; reuse) ----
  float* mm = (float*)&smem[65536];           // m[set][kq][32], l at +256 floats
  if (l < 32) {
    mm[(0 * 4 + kq) * 32 + l] = mA;
    mm[(1 * 4 + kq) * 32 + l] = mB;
    mm[256 + (0 * 4 + kq) * 32 + l] = lA;
    mm[256 + (1 * 4 + kq) * 32 + l] = lB;
  }
  __syncthreads();
  float MA = mm[0 * 32 + q31], MB = mm[4 * 32 + q31];
  #pragma unroll
  for (int j = 1; j < 4; ++j) {
    MA = fmaxf(MA, mm[(0 * 4 + j) * 32 + q31]);
    MB = fmaxf(MB, mm[(1 * 4 + j) * 32 + q31]);
  }
  float LA = 0.f, LB = 0.f;
  #pragma unroll
  for (int j = 0; j < 4; ++j) {
    LA += mm[256 + (0 * 4 + j) * 32 + q31] * __builtin_amdgcn_exp2f(mm[(0 * 4 + j) * 32 + q31] - MA);
    LB += mm[256 + (1 * 4 + j) * 32 + q31] * __builtin_amdgcn_exp2f(mm[(1 * 4 + j) * 32 + q31] - MB);
  }
  const float aA = __builtin_amdgcn_exp2f(mA - MA), liA = 1.f / LA;
  const float aB = __builtin_amdgcn_exp2f(mB - MB), liB = 1.f / LB;

  float* obuf = (float*)&smem[0];             // [64 q][64 d] f32
  #pragma unroll
  for (int round = 3; round >= 0; --round) {
    if (kq == round) {
      #pragma unroll
      for (int r = 0; r < 16; ++r) {
        const int qr = (r & 3) + 8 * (r >> 2) + hi4;
        const float arA = __shfl(aA, qr, 64);
        const float arB = __shfl(aB, qr, 64);
        float* pa0 = &obuf[qr * 64 + q31];
        float* pa1 = &obuf[qr * 64 + 32 + q31];
        float* pb0 = &obuf[(32 + qr) * 64 + q31];
        float* pb1 = &obuf[(32 + qr) * 64 + 32 + q31];
        if (round == 3) {
          *pa0 = accA0[r] * arA; *pa1 = accA1[r] * arA;
          *pb0 = accB0[r] * arB; *pb1 = accB1[r] * arB;
        } else if (round > 0) {
          *pa0 += accA0[r] * arA; *pa1 += accA1[r] * arA;
          *pb0 += accB0[r] * arB; *pb1 += accB1[r] * arB;
        } else {
          const float lrA = __shfl(liA, qr, 64);
          const float lrB = __shfl(liB, qr, 64);
          const int rowA = qt * 64 + qr, rowB = qt * 64 + 32 + qr;
          og[(size_t)rowA * DIM + h * HD + q31] = f2b((accA0[r] * arA + *pa0) * lrA);
          og[(size_t)rowA * DIM + h * HD + 32 + q31] = f2b((accA1[r] * arA + *pa1) * lrA);
          og[(size_t)rowB * DIM + h * HD + q31] = f2b((accB0[r] * arB + *pb0) * lrB);
          og[(size_t)rowB * DIM + h * HD + 32 + q31] = f2b((accB1[r] * arB + *pb1) * lrB);
        }
      }
    }
    __syncthreads();
  }
}

// ---------- LayerNorm + per-modality affine + scatter (sums split-K partials) ----------
__global__ __launch_bounds__(256) void ln_scatter(const float* __restrict__ oa,
                                                  const float* __restrict__ ob,
                                                  const float* __restrict__ lnw,
                                                  const float* __restrict__ lnb,
                                                  const int* __restrict__ perm,
                                                  const int* __restrict__ cntp,
                                                  float* __restrict__ out) {
  const int i = blockIdx.x;
  const int tid = threadIdx.x, w = tid >> 6, l = tid & 63;
  const int mod = (i < cntp[0]) ? 0 : 1;
  float4 va = ((const float4*)(oa + (size_t)i * DIM))[tid];
  float4 vb = ((const float4*)(ob + (size_t)i * DIM))[tid];
  float4 v;
  v.x = va.x + vb.x; v.y = va.y + vb.y; v.z = va.z + vb.z; v.w = va.w + vb.w;
  float s = v.x + v.y + v.z + v.w;
  float ss = v.x * v.x + v.y * v.y + v.z * v.z + v.w * v.w;
  #pragma unroll
  for (int off = 1; off < 64; off <<= 1) {
    s += __shfl_xor(s, off, 64);
    ss += __shfl_xor(ss, off, 64);
  }
  __shared__ float rs4[4], rss4[4];
  if (l == 0) { rs4[w] = s; rss4[w] = ss; }
  __syncthreads();
  const float st = rs4[0] + rs4[1] + rs4[2] + rs4[3];
  const float sst = rss4[0] + rss4[1] + rss4[2] + rss4[3];
  const float mu = st * (1.f / DIM);
  const float var = sst * (1.f / DIM) - mu * mu;
  const float rstd = rsqrtf(var + 1e-5f);
  const int drow = perm[i];
  float4 g = ((const float4*)(lnw + (size_t)mod * DIM))[tid];
  float4 b = ((const float4*)(lnb + (size_t)mod * DIM))[tid];
  float4 rr;
  rr.x = (v.x - mu) * rstd * g.x + b.x;
  rr.y = (v.y - mu) * rstd * g.y + b.y;
  rr.z = (v.z - mu) * rstd * g.z + b.z;
  rr.w = (v.w - mu) * rstd * g.w + b.w;
  ((float4*)(out + (size_t)drow * DIM))[tid] = rr;
}

// ---------- launch ----------
extern "C" void kernel_launch(void* const* d_in, const int* in_sizes, int n_in,
                              void* d_out, int out_size, void* d_ws, size_t ws_size,
                              hipStream_t stream) {
  const float* x = (const float*)d_in[0];
  const void* masks = d_in[1];
  const float* wq = (const float*)d_in[3];
  const float* wk = (const float*)d_in[4];
  const float* wv = (const float*)d_in[5];
  const float* wo = (const float*)d_in[6];
  const float* lnw = (const float*)d_in[7];
  const float* lnb = (const float*)d_in[8];

  char* ws = (char*)d_ws;
  int* perm = (int*)(ws + OFF_PERM);
  int* cnt = (int*)(ws + OFF_CNT);
  u16* wT = (u16*)(ws + OFF_WT);
  u16* q = (u16*)(ws + OFF_Q);
  u16* k = (u16*)(ws + OFF_K);
  u16* vT = (u16*)(ws + OFF_VT);
  u16* at = (u16*)(ws + OFF_AT);
  float* o = (float*)(ws + OFF_O);
  float* o2 = (float*)(ws + OFF_O2);
  float* out = (float*)d_out;

  wcast_prep<<<dim3(32, 32, 9), dim3(32, 8), 0, stream>>>(wq, wk, wv, wo, wT, masks, perm, cnt);
  gemm_qkv<<<dim3(8, 32, 3), 256, 0, stream>>>(x, perm, wT, QSCALE, q, k, vT, cnt);
  attn_fwd<<<512, 256, 0, stream>>>(q, k, vT, at);
  gemm_out<<<dim3(16, 32, 2), 256, 0, stream>>>(at, wT, o, o2, cnt);
  ln_scatter<<<N_TOK, 256, 0, stream>>>(o, o2, lnw, lnb, perm, cnt, out);
}

// Round 10
// 91.513 us; speedup vs baseline: 1.2268x; 1.2268x over previous
//
#include <hip/hip_runtime.h>

typedef __attribute__((ext_vector_type(8))) short short8v;
typedef __attribute__((ext_vector_type(4))) float f32x4;
typedef __attribute__((ext_vector_type(16))) float f32x16;
typedef unsigned short u16;
typedef unsigned int u32;

#define MFMA __builtin_amdgcn_mfma_f32_16x16x32_bf16
#define MFMA32 __builtin_amdgcn_mfma_f32_32x32x16_bf16

// ---------- helpers ----------
__device__ __forceinline__ u16 f2b(float f) {
  u32 u = __float_as_uint(f);
  u = (u + 0x7FFFu + ((u >> 16) & 1u)) >> 16;
  return (u16)u;
}
__device__ __forceinline__ void g2l16(const void* g, void* l) {
  __builtin_amdgcn_global_load_lds(
      (const __attribute__((address_space(1))) unsigned int*)g,
      (__attribute__((address_space(3))) unsigned int*)l, 16, 0, 0);
}

// sizes
#define N_TOK 2048
#define DIM 1024
#define NH 16
#define HD 64

// Q pre-scale: hd^-0.5 * log2(e)  (softmax runs in exp2 domain)
#define QSCALE 0.18033688011112042f

// workspace layout (bytes)
#define OFF_PERM 0
#define OFF_CNT 8192
#define OFF_XPB 16384
#define OFF_WT (OFF_XPB + 4194304)          // 16 MB: [tensor][expert][1024][1024] bf16, WT[n][k]
#define OFF_Q (OFF_WT + 16777216)
#define OFF_K (OFF_Q + 4194304)
#define OFF_VT (OFF_K + 4194304)            // [16][64][2048] bf16
#define OFF_AT (OFF_VT + 4194304)
#define OFF_O (OFF_AT + 4194304)            // f32 [2048][1024]
#define OFF_O2 (OFF_O + 8388608)            // f32 [2048][1024] split-K partial

// ---------- fused: weight transpose-cast (z<8) + prep partition (z==8) ----------
__global__ __launch_bounds__(256) void wcast_prep(const float* __restrict__ wq,
                                                  const float* __restrict__ wk,
                                                  const float* __restrict__ wv,
                                                  const float* __restrict__ wo,
                                                  u16* __restrict__ wT,
                                                  const void* __restrict__ masks,
                                                  int* __restrict__ perm,
                                                  int* __restrict__ cnt) {
  __shared__ float t[32][33];
  __shared__ u32 red[256];
  __shared__ int scan[256];
  const int tx = threadIdx.x, ty = threadIdx.y;
  if (blockIdx.z == 8) {
    if (blockIdx.x != 0 || blockIdx.y != 0) return;
    const int tid = ty * 32 + tx;
    const u32* mw = (const u32*)masks;
    u32 mx = 0;
    for (int i = tid; i < 1024; i += 256) { u32 v = mw[i]; mx = mx > v ? mx : v; }
    red[tid] = mx;
    __syncthreads();
    for (int off = 128; off; off >>= 1) {
      if (tid < off) red[tid] = red[tid] > red[tid + off] ? red[tid] : red[tid + off];
      __syncthreads();
    }
    const bool isbyte = red[0] > 1u;
    int md[8];
    int c0loc = 0;
    #pragma unroll
    for (int j = 0; j < 8; ++j) {
      const int n = tid * 8 + j;
      int m1;
      if (isbyte) m1 = ((const unsigned char*)masks)[N_TOK + n] != 0;
      else        m1 = mw[N_TOK + n] != 0;
      md[j] = m1;
      c0loc += (m1 == 0);
    }
    scan[tid] = c0loc;
    __syncthreads();
    for (int off = 1; off < 256; off <<= 1) {
      int v = (tid >= off) ? scan[tid - off] : 0;
      __syncthreads();
      scan[tid] += v;
      __syncthreads();
    }
    const int incl = scan[tid];
    const int total0 = scan[255];
    const int excl0 = incl - c0loc;
    int p0 = excl0;
    int p1 = total0 + (tid * 8 - excl0);
    #pragma unroll
    for (int j = 0; j < 8; ++j) {
      const int n = tid * 8 + j;
      if (!md[j]) perm[p0++] = n; else perm[p1++] = n;
    }
    if (tid == 0) cnt[0] = total0;
    return;
  }
  const int mat = blockIdx.z;               // tensor*2 + expert
  const int tensor = mat >> 1, expert = mat & 1;
  const float* src = (tensor == 0) ? wq : (tensor == 1) ? wk : (tensor == 2) ? wv : wo;
  src += (size_t)expert * (1 << 20);
  u16* dst = wT + ((size_t)mat << 20);
  const int k0 = blockIdx.x * 32, n0 = blockIdx.y * 32;
  #pragma unroll
  for (int r = 0; r < 4; ++r)
    t[ty + 8 * r][tx] = src[(size_t)(k0 + ty + 8 * r) * DIM + n0 + tx];
  __syncthreads();
  // vectorized u32-pair stores: thread -> (row=n, 2 k-pairs)
  const int tid = ty * 32 + tx;
  const int row = tid >> 3, pr = tid & 7;
  u32* dst32 = (u32*)(dst + (size_t)(n0 + row) * DIM + k0);
  #pragma unroll
  for (int j = 0; j < 2; ++j) {
    const int kp = pr + j * 8;
    u32 val;
    asm("v_cvt_pk_bf16_f32 %0, %1, %2" : "=v"(val)
        : "v"(t[2 * kp][row]), "v"(t[2 * kp + 1][row]));
    dst32[kp] = val;
  }
}

// ---------- gather + cast x -> xp bf16 ----------
__global__ __launch_bounds__(256) void gather_cast(const float* __restrict__ x,
                                                   const int* __restrict__ perm,
                                                   u16* __restrict__ xpb) {
  const int i = blockIdx.x;
  const int src = perm[i];
  const int tid = threadIdx.x;
  float4 v = ((const float4*)(x + (size_t)src * DIM))[tid];
  ushort4 o;
  o.x = f2b(v.x); o.y = f2b(v.y); o.z = f2b(v.z); o.w = f2b(v.w);
  ((ushort4*)(xpb + (size_t)i * DIM))[tid] = o;
}

// ---------- QKV GEMM: BK=64, T2 swizzle; z==2 writes V^T via LDS transpose ----------
__global__ __launch_bounds__(256) void gemm_qkv(const u16* __restrict__ X,
                                                const u16* __restrict__ WTall,
                                                float qscale,
                                                u16* __restrict__ oq,
                                                u16* __restrict__ ok,
                                                u16* __restrict__ vT,
                                                const int* __restrict__ cntp) {
  const int z = blockIdx.z;                  // 0=q 1=k 2=v
  const int e = blockIdx.y >> 4;
  const int mt = blockIdx.y & 15;
  const int c0 = cntp[0];
  const int lo = e ? c0 : 0;
  const int hi = e ? N_TOK : c0;
  const int rb = mt * 128;
  if (rb >= hi || rb + 128 <= lo) return;
  const int cb = blockIdx.x * 128;
  const u16* W = WTall + ((size_t)(z * 2 + e) << 20);
  const float scl = (z == 0) ? qscale : 1.f;

  const int tid = threadIdx.x;
  const int w = tid >> 6, l = tid & 63, lg = l >> 4, ln = l & 15;
  const int wm = (w >> 1) * 64, wn = (w & 1) * 64;

  __shared__ __align__(16) char smem[65536];   // 2 bufs x (A 16K + B 16K)

  auto stage = [&](int it, int b_) {
    #pragma unroll
    for (int c = 0; c < 8; ++c) {
      const int j = tid + c * 256;             // 0..2047
      const int isB = j >> 10;
      const int cc = j & 1023;
      const int row = cc >> 3;
      const int colb = ((cc & 7) * 16) ^ ((row & 7) << 4);  // pre-swizzled source
      const char* base = isB ? (const char*)W + (size_t)(cb + row) * 2048
                             : (const char*)X + (size_t)(rb + row) * 2048;
      g2l16(base + it * 128 + colb, &smem[b_ * 32768 + isB * 16384 + cc * 16]);
    }
  };

  f32x4 acc[4][4];
  #pragma unroll
  for (int i = 0; i < 4; ++i)
    #pragma unroll
    for (int j = 0; j < 4; ++j) acc[i][j] = (f32x4){0.f, 0.f, 0.f, 0.f};

  const int aswz = (ln & 7) << 4;
  stage(0, 0);
  __syncthreads();
  for (int ii = 0; ii < 16; ++ii) {
    const int b_ = ii & 1;
    if (ii < 15) stage(ii + 1, b_ ^ 1);
    #pragma unroll
    for (int ks = 0; ks < 2; ++ks) {
      short8v a[4], bb[4];
      #pragma unroll
      for (int mi = 0; mi < 4; ++mi)
        a[mi] = *(const short8v*)&smem[b_ * 32768 + (wm + mi * 16 + ln) * 128 +
                                       ((ks * 64 + lg * 16) ^ aswz)];
      #pragma unroll
      for (int ni = 0; ni < 4; ++ni)
        bb[ni] = *(const short8v*)&smem[b_ * 32768 + 16384 + (wn + ni * 16 + ln) * 128 +
                                        ((ks * 64 + lg * 16) ^ aswz)];
      __builtin_amdgcn_s_setprio(1);
      #pragma unroll
      for (int mi = 0; mi < 4; ++mi)
        #pragma unroll
        for (int ni = 0; ni < 4; ++ni)
          acc[mi][ni] = MFMA(a[mi], bb[ni], acc[mi][ni], 0, 0, 0);
      __builtin_amdgcn_s_setprio(0);
    }
    __syncthreads();
  }

  if (z < 2) {
    u16* OUT = z ? ok : oq;
    #pragma unroll
    for (int mi = 0; mi < 4; ++mi) {
      #pragma unroll
      for (int r = 0; r < 4; ++r) {
        const int row = rb + wm + mi * 16 + lg * 4 + r;
        if (row >= lo && row < hi) {
          #pragma unroll
          for (int ni = 0; ni < 4; ++ni)
            OUT[(size_t)row * DIM + cb + wn + ni * 16 + ln] = f2b(acc[mi][ni][r] * scl);
        }
      }
    }
  } else {
    // V^T epilogue: transpose acc [token][dim] -> vT[dim][token] via LDS.
    #pragma unroll
    for (int mi = 0; mi < 4; ++mi)
      #pragma unroll
      for (int ni = 0; ni < 4; ++ni) {
        const int dim = wn + ni * 16 + ln;
        const int tok = wm + mi * 16 + lg * 4;
        u32 p01, p23;
        asm("v_cvt_pk_bf16_f32 %0, %1, %2" : "=v"(p01) : "v"(acc[mi][ni][0]), "v"(acc[mi][ni][1]));
        asm("v_cvt_pk_bf16_f32 %0, %1, %2" : "=v"(p23) : "v"(acc[mi][ni][2]), "v"(acc[mi][ni][3]));
        *(uint2*)&smem[dim * 264 + tok * 2] = make_uint2(p01, p23);
      }
    __syncthreads();
    #pragma unroll 4
    for (int rr = 0; rr < 32; ++rr) {
      const int dim = w * 32 + rr;
      const u32 val = *(const u32*)&smem[dim * 264 + l * 4];
      const int tok = rb + 2 * l;
      u16* dst = vT + (size_t)(cb + dim) * 2048 + tok;
      if (tok >= lo && tok + 2 <= hi) {
        *(u32*)dst = val;
      } else {
        if (tok >= lo && tok < hi) dst[0] = (u16)(val & 0xFFFFu);
        if (tok + 1 >= lo && tok + 1 < hi) dst[1] = (u16)(val >> 16);
      }
    }
  }
}

// ---------- out-proj GEMM: 128x64 tile, BK=64, split-K2, f32 partials ----------
__global__ __launch_bounds__(256) void gemm_out(const u16* __restrict__ X,
                                                const u16* __restrict__ WTall,
                                                float* __restrict__ o0,
                                                float* __restrict__ o1,
                                                const int* __restrict__ cntp) {
  const int z = blockIdx.z;                  // K-half
  const int e = blockIdx.y >> 4;
  const int mt = blockIdx.y & 15;
  const int c0 = cntp[0];
  const int lo = e ? c0 : 0;
  const int hi = e ? N_TOK : c0;
  const int rb = mt * 128;
  if (rb >= hi || rb + 128 <= lo) return;
  const int cb = blockIdx.x * 64;
  float* OUT = z ? o1 : o0;
  const u16* W = WTall + ((size_t)(6 + e) << 20);
  const int kstart = z * 8;

  const int tid = threadIdx.x;
  const int w = tid >> 6, l = tid & 63, lg = l >> 4, ln = l & 15;
  const int wm = w * 32;

  __shared__ __align__(16) char smem[49152];   // 2 bufs x (A 16K + B 8K)

  auto stage = [&](int it, int b_) {
    #pragma unroll
    for (int c = 0; c < 6; ++c) {
      const int j = tid + c * 256;             // 0..1535
      const int isB = j >= 1024;
      const int cc = isB ? (j - 1024) : j;
      const int row = cc >> 3;
      const int colb = ((cc & 7) * 16) ^ ((row & 7) << 4);
      const char* base = isB ? (const char*)W + (size_t)(cb + row) * 2048
                             : (const char*)X + (size_t)(rb + row) * 2048;
      g2l16(base + it * 128 + colb, &smem[b_ * 24576 + isB * 16384 + cc * 16]);
    }
  };

  f32x4 acc[2][4];
  #pragma unroll
  for (int i = 0; i < 2; ++i)
    #pragma unroll
    for (int j = 0; j < 4; ++j) acc[i][j] = (f32x4){0.f, 0.f, 0.f, 0.f};

  const int aswz = (ln & 7) << 4;
  stage(kstart, 0);
  __syncthreads();
  for (int ii = 0; ii < 8; ++ii) {
    const int b_ = ii & 1;
    if (ii < 7) stage(kstart + ii + 1, b_ ^ 1);
    #pragma unroll
    for (int ks = 0; ks < 2; ++ks) {
      short8v a[2], bb[4];
      #pragma unroll
      for (int mi = 0; mi < 2; ++mi)
        a[mi] = *(const short8v*)&smem[b_ * 24576 + (wm + mi * 16 + ln) * 128 +
                                       ((ks * 64 + lg * 16) ^ aswz)];
      #pragma unroll
      for (int ni = 0; ni < 4; ++ni)
        bb[ni] = *(const short8v*)&smem[b_ * 24576 + 16384 + (ni * 16 + ln) * 128 +
                                        ((ks * 64 + lg * 16) ^ aswz)];
      __builtin_amdgcn_s_setprio(1);
      #pragma unroll
      for (int mi = 0; mi < 2; ++mi)
        #pragma unroll
        for (int ni = 0; ni < 4; ++ni)
          acc[mi][ni] = MFMA(a[mi], bb[ni], acc[mi][ni], 0, 0, 0);
      __builtin_amdgcn_s_setprio(0);
    }
    __syncthreads();
  }

  #pragma unroll
  for (int mi = 0; mi < 2; ++mi) {
    #pragma unroll
    for (int r = 0; r < 4; ++r) {
      const int row = rb + wm + mi * 16 + lg * 4 + r;
      if (row >= lo && row < hi) {
        #pragma unroll
        for (int ni = 0; ni < 4; ++ni)
          OUT[(size_t)row * DIM + cb + ni * 16 + ln] = acc[mi][ni][r];
      }
    }
  }
}

// ---------- flash attention: barrier-free, wave-private K/V, depth-2 pipeline,
// single merged defer-max branch per iter (schedulable A/B interleave) ----------
__global__ __launch_bounds__(256, 2) void attn_fwd(const u16* __restrict__ qg,
                                                   const u16* __restrict__ kg,
                                                   const u16* __restrict__ vTg,
                                                   u16* __restrict__ og) {
  const int bid = blockIdx.x;
  const int wg = (bid & 7) * 64 + (bid >> 3);   // bijective XCD swizzle (512 = 8*64)
  const int qt = wg & 31, h = wg >> 5;
  const int tid = threadIdx.x, kq = tid >> 6, l = tid & 63;
  const int q31 = l & 31, hi = l >> 5;
  const int hi16 = hi * 16, hi4 = hi * 4;

  __shared__ __align__(16) char smem[67584];   // 4 waves x 16KB dbuf + 2KB merge
  const int base = kq * 16384;

  // per-lane staging source bases (inverse-swizzled so LDS writes are linear)
  const int lr3 = l >> 3, lc3 = l & 7;
  const char* baseK = (const char*)kg + (size_t)(kq * 512 + lr3) * 2048 + h * 128 +
                      ((lc3 << 4) ^ (lr3 << 4));
  const int cpr = lc3 ^ lr3;                  // swizzled col/16 for V
  const int dhalf = (cpr >> 2) & 1;
  const char* baseV = (const char*)vTg + (size_t)(h * 64 + lr3 + dhalf * 32) * 4096 +
                      kq * 1024 + ((cpr & 3) << 4);

  // Q fragments (B-operand), 2 sets of 32 q-cols
  const char* qb0 = (const char*)qg + (size_t)(qt * 64 + q31) * 2048 + h * 128;
  short8v qfA[4], qfB[4];
  #pragma unroll
  for (int t = 0; t < 4; ++t) {
    qfA[t] = *(const short8v*)(qb0 + t * 32 + hi16);
    qfB[t] = *(const short8v*)(qb0 + 65536 + t * 32 + hi16);
  }

  uint4 rk0, rk1, rk2, rk3, rv0, rv1, rv2, rv3;
  auto loadKV = [&](int it) {
    const char* pk = baseK + (size_t)it * 65536;   // 32 key-rows x 2048B
    rk0 = *(const uint4*)(pk);
    rk1 = *(const uint4*)(pk + 16384);
    rk2 = *(const uint4*)(pk + 32768);
    rk3 = *(const uint4*)(pk + 49152);
    const char* pv = baseV + it * 64;              // 32 keys x 2B
    rv0 = *(const uint4*)(pv);
    rv1 = *(const uint4*)(pv + 32768);
    rv2 = *(const uint4*)(pv + 65536);
    rv3 = *(const uint4*)(pv + 98304);
  };
  auto writeK = [&](int b_) {
    const int Kb = base + b_ * 8192;
    *(uint4*)&smem[Kb + 0 + l * 16] = rk0;
    *(uint4*)&smem[Kb + 1024 + l * 16] = rk1;
    *(uint4*)&smem[Kb + 2048 + l * 16] = rk2;
    *(uint4*)&smem[Kb + 3072 + l * 16] = rk3;
  };
  auto writeV = [&](int b_) {
    const int Vb = base + b_ * 8192 + 4096;
    *(uint4*)&smem[Vb + 0 + l * 16] = rv0;
    *(uint4*)&smem[Vb + 1024 + l * 16] = rv1;
    *(uint4*)&smem[Vb + 2048 + l * 16] = rv2;
    *(uint4*)&smem[Vb + 3072 + l * 16] = rv3;
  };

  float mA = -1e30f, lA = 0.f, mB = -1e30f, lB = 0.f;
  f32x16 accA0, accA1, accB0, accB1;
  #pragma unroll
  for (int r = 0; r < 16; ++r) { accA0[r] = 0.f; accA1[r] = 0.f; accB0[r] = 0.f; accB1[r] = 0.f; }

  struct PA { short8v p0, p1; };

  // paired softmax: single merged rescale branch -> big schedulable block
  auto softmax_pair = [&](f32x16& sA_, f32x16& sB_, PA& oA, PA& oB) {
    float tA0 = fmaxf(fmaxf(sA_[0], sA_[1]), fmaxf(sA_[2], sA_[3]));
    float tB0 = fmaxf(fmaxf(sB_[0], sB_[1]), fmaxf(sB_[2], sB_[3]));
    float tA1 = fmaxf(fmaxf(sA_[4], sA_[5]), fmaxf(sA_[6], sA_[7]));
    float tB1 = fmaxf(fmaxf(sB_[4], sB_[5]), fmaxf(sB_[6], sB_[7]));
    float tA2 = fmaxf(fmaxf(sA_[8], sA_[9]), fmaxf(sA_[10], sA_[11]));
    float tB2 = fmaxf(fmaxf(sB_[8], sB_[9]), fmaxf(sB_[10], sB_[11]));
    float tA3 = fmaxf(fmaxf(sA_[12], sA_[13]), fmaxf(sA_[14], sA_[15]));
    float tB3 = fmaxf(fmaxf(sB_[12], sB_[13]), fmaxf(sB_[14], sB_[15]));
    float tmA = fmaxf(fmaxf(tA0, tA1), fmaxf(tA2, tA3));
    float tmB = fmaxf(fmaxf(tB0, tB1), fmaxf(tB2, tB3));
    tmA = fmaxf(tmA, __shfl_xor(tmA, 32, 64));
    tmB = fmaxf(tmB, __shfl_xor(tmB, 32, 64));
    const bool okb = (tmA <= mA + 11.0f) && (tmB <= mB + 11.0f);
    if (!__all(okb)) {                         // T13 defer-max, merged
      const float mnA = fmaxf(mA, tmA), mnB = fmaxf(mB, tmB);
      const float alA = __builtin_amdgcn_exp2f(mA - mnA);
      const float alB = __builtin_amdgcn_exp2f(mB - mnB);
      mA = mnA; mB = mnB; lA *= alA; lB *= alB;
      #pragma unroll
      for (int r = 0; r < 16; ++r) {
        const int qr = (r & 3) + 8 * (r >> 2) + hi4;
        const float arA = __shfl(alA, qr, 64);
        const float arB = __shfl(alB, qr, 64);
        accA0[r] *= arA; accA1[r] *= arA;
        accB0[r] *= arB; accB1[r] *= arB;
      }
    }
    float pA_[16], pB_[16];
    #pragma unroll
    for (int r = 0; r < 16; ++r) {
      pA_[r] = __builtin_amdgcn_exp2f(sA_[r] - mA);
      pB_[r] = __builtin_amdgcn_exp2f(sB_[r] - mB);
    }
    float rsA = ((pA_[0] + pA_[1]) + (pA_[2] + pA_[3])) + ((pA_[4] + pA_[5]) + (pA_[6] + pA_[7])) +
                (((pA_[8] + pA_[9]) + (pA_[10] + pA_[11])) + ((pA_[12] + pA_[13]) + (pA_[14] + pA_[15])));
    float rsB = ((pB_[0] + pB_[1]) + (pB_[2] + pB_[3])) + ((pB_[4] + pB_[5]) + (pB_[6] + pB_[7])) +
                (((pB_[8] + pB_[9]) + (pB_[10] + pB_[11])) + ((pB_[12] + pB_[13]) + (pB_[14] + pB_[15])));
    rsA += __shfl_xor(rsA, 32, 64);
    rsB += __shfl_xor(rsB, 32, 64);
    lA += rsA;
    lB += rsB;
    u32 a0, a1, a2, a3, a4, a5, a6, a7, b0, b1, b2, b3, b4, b5, b6, b7;
    asm("v_cvt_pk_bf16_f32 %0, %1, %2" : "=v"(a0) : "v"(pA_[0]), "v"(pA_[1]));
    asm("v_cvt_pk_bf16_f32 %0, %1, %2" : "=v"(a1) : "v"(pA_[2]), "v"(pA_[3]));
    asm("v_cvt_pk_bf16_f32 %0, %1, %2" : "=v"(a2) : "v"(pA_[4]), "v"(pA_[5]));
    asm("v_cvt_pk_bf16_f32 %0, %1, %2" : "=v"(a3) : "v"(pA_[6]), "v"(pA_[7]));
    asm("v_cvt_pk_bf16_f32 %0, %1, %2" : "=v"(a4) : "v"(pA_[8]), "v"(pA_[9]));
    asm("v_cvt_pk_bf16_f32 %0, %1, %2" : "=v"(a5) : "v"(pA_[10]), "v"(pA_[11]));
    asm("v_cvt_pk_bf16_f32 %0, %1, %2" : "=v"(a6) : "v"(pA_[12]), "v"(pA_[13]));
    asm("v_cvt_pk_bf16_f32 %0, %1, %2" : "=v"(a7) : "v"(pA_[14]), "v"(pA_[15]));
    asm("v_cvt_pk_bf16_f32 %0, %1, %2" : "=v"(b0) : "v"(pB_[0]), "v"(pB_[1]));
    asm("v_cvt_pk_bf16_f32 %0, %1, %2" : "=v"(b1) : "v"(pB_[2]), "v"(pB_[3]));
    asm("v_cvt_pk_bf16_f32 %0, %1, %2" : "=v"(b2) : "v"(pB_[4]), "v"(pB_[5]));
    asm("v_cvt_pk_bf16_f32 %0, %1, %2" : "=v"(b3) : "v"(pB_[6]), "v"(pB_[7]));
    asm("v_cvt_pk_bf16_f32 %0, %1, %2" : "=v"(b4) : "v"(pB_[8]), "v"(pB_[9]));
    asm("v_cvt_pk_bf16_f32 %0, %1, %2" : "=v"(b5) : "v"(pB_[10]), "v"(pB_[11]));
    asm("v_cvt_pk_bf16_f32 %0, %1, %2" : "=v"(b6) : "v"(pB_[12]), "v"(pB_[13]));
    asm("v_cvt_pk_bf16_f32 %0, %1, %2" : "=v"(b7) : "v"(pB_[14]), "v"(pB_[15]));
    asm volatile("v_permlane32_swap_b32 %0, %1" : "+v"(a0), "+v"(a2));
    asm volatile("v_permlane32_swap_b32 %0, %1" : "+v"(a1), "+v"(a3));
    asm volatile("v_permlane32_swap_b32 %0, %1" : "+v"(a4), "+v"(a6));
    asm volatile("v_permlane32_swap_b32 %0, %1" : "+v"(a5), "+v"(a7));
    asm volatile("v_permlane32_swap_b32 %0, %1" : "+v"(b0), "+v"(b2));
    asm volatile("v_permlane32_swap_b32 %0, %1" : "+v"(b1), "+v"(b3));
    asm volatile("v_permlane32_swap_b32 %0, %1" : "+v"(b4), "+v"(b6));
    asm volatile("v_permlane32_swap_b32 %0, %1" : "+v"(b5), "+v"(b7));
    union { u32 u[4]; short8v s; } uA0, uA1, uB0, uB1;
    uA0.u[0] = a0; uA0.u[1] = a1; uA0.u[2] = a2; uA0.u[3] = a3;
    uA1.u[0] = a4; uA1.u[1] = a5; uA1.u[2] = a6; uA1.u[3] = a7;
    uB0.u[0] = b0; uB0.u[1] = b1; uB0.u[2] = b2; uB0.u[3] = b3;
    uB1.u[0] = b4; uB1.u[1] = b5; uB1.u[2] = b6; uB1.u[3] = b7;
    oA.p0 = uA0.s; oA.p1 = uA1.s;
    oB.p0 = uB0.s; oB.p1 = uB1.s;
  };

  const int kswz = (q31 & 7) << 4;
  loadKV(0);
  writeK(0);
  writeV(0);
  loadKV(1);

  #pragma unroll 1
  for (int it = 0; it < 16; ++it) {
    const int cur = it & 1, nxt = cur ^ 1;
    const int Kb = base + cur * 8192, Vb = Kb + 4096;
    short8v kf0 = *(const short8v*)&smem[Kb + q31 * 128 + ((0 + hi16) ^ kswz)];
    short8v kf1 = *(const short8v*)&smem[Kb + q31 * 128 + ((32 + hi16) ^ kswz)];
    short8v kf2 = *(const short8v*)&smem[Kb + q31 * 128 + ((64 + hi16) ^ kswz)];
    short8v kf3 = *(const short8v*)&smem[Kb + q31 * 128 + ((96 + hi16) ^ kswz)];
    f32x16 sA, sB;
    #pragma unroll
    for (int r = 0; r < 16; ++r) { sA[r] = 0.f; sB[r] = 0.f; }
    __builtin_amdgcn_s_setprio(1);
    sA = MFMA32(kf0, qfA[0], sA, 0, 0, 0);
    sB = MFMA32(kf0, qfB[0], sB, 0, 0, 0);
    sA = MFMA32(kf1, qfA[1], sA, 0, 0, 0);
    sB = MFMA32(kf1, qfB[1], sB, 0, 0, 0);
    sA = MFMA32(kf2, qfA[2], sA, 0, 0, 0);
    sB = MFMA32(kf2, qfB[2], sB, 0, 0, 0);
    sA = MFMA32(kf3, qfA[3], sA, 0, 0, 0);
    sB = MFMA32(kf3, qfB[3], sB, 0, 0, 0);
    __builtin_amdgcn_s_setprio(0);
    if (it < 15) writeK(nxt);

    PA pA, pB;
    softmax_pair(sA, sB, pA, pB);

    short8v vf00 = *(const short8v*)&smem[Vb + q31 * 128 + ((0 + hi16) ^ kswz)];
    short8v vf01 = *(const short8v*)&smem[Vb + q31 * 128 + ((64 + hi16) ^ kswz)];
    short8v vf10 = *(const short8v*)&smem[Vb + q31 * 128 + ((32 + hi16) ^ kswz)];
    short8v vf11 = *(const short8v*)&smem[Vb + q31 * 128 + ((96 + hi16) ^ kswz)];
    __builtin_amdgcn_s_setprio(1);
    accA0 = MFMA32(pA.p0, vf00, accA0, 0, 0, 0);
    accA1 = MFMA32(pA.p0, vf01, accA1, 0, 0, 0);
    accB0 = MFMA32(pB.p0, vf00, accB0, 0, 0, 0);
    accB1 = MFMA32(pB.p0, vf01, accB1, 0, 0, 0);
    accA0 = MFMA32(pA.p1, vf10, accA0, 0, 0, 0);
    accA1 = MFMA32(pA.p1, vf11, accA1, 0, 0, 0);
    accB0 = MFMA32(pB.p1, vf10, accB0, 0, 0, 0);
    accB1 = MFMA32(pB.p1, vf11, accB1, 0, 0, 0);
    __builtin_amdgcn_s_setprio(0);
    if (it < 15) writeV(nxt);
    if (it < 14) loadKV(it + 2);
  }
  __syncthreads();

  // ---- 4-way split-K merge (staging LDS dead; reuse) ----
  float* mm = (float*)&smem[65536];           // m[set][kq][32], l at +256 floats
  if (l < 32) {
    mm[(0 * 4 + kq) * 32 + l] = mA;
    mm[(1 * 4 + kq) * 32 + l] = mB;
    mm[256 + (0 * 4 + kq) * 32 + l] = lA;
    mm[256 + (1 * 4 + kq) * 32 + l] = lB;
  }
  __syncthreads();
  float MA = mm[0 * 32 + q31], MB = mm[4 * 32 + q31];
  #pragma unroll
  for (int j = 1; j < 4; ++j) {
    MA = fmaxf(MA, mm[(0 * 4 + j) * 32 + q31]);
    MB = fmaxf(MB, mm[(1 * 4 + j) * 32 + q31]);
  }
  float LA = 0.f, LB = 0.f;
  #pragma unroll
  for (int j = 0; j < 4; ++j) {
    LA += mm[256 + (0 * 4 + j) * 32 + q31] * __builtin_amdgcn_exp2f(mm[(0 * 4 + j) * 32 + q31] - MA);
    LB += mm[256 + (1 * 4 + j) * 32 + q31] * __builtin_amdgcn_exp2f(mm[(1 * 4 + j) * 32 + q31] - MB);
  }
  const float aA = __builtin_amdgcn_exp2f(mA - MA), liA = 1.f / LA;
  const float aB = __builtin_amdgcn_exp2f(mB - MB), liB = 1.f / LB;

  float* obuf = (float*)&smem[0];             // [64 q][64 d] f32
  #pragma unroll
  for (int round = 3; round >= 0; --round) {
    if (kq == round) {
      #pragma unroll
      for (int r = 0; r < 16; ++r) {
        const int qr = (r & 3) + 8 * (r >> 2) + hi4;
        const float arA = __shfl(aA, qr, 64);
        const float arB = __shfl(aB, qr, 64);
        float* pa0 = &obuf[qr * 64 + q31];
        float* pa1 = &obuf[qr * 64 + 32 + q31];
        float* pb0 = &obuf[(32 + qr) * 64 + q31];
        float* pb1 = &obuf[(32 + qr) * 64 + 32 + q31];
        if (round == 3) {
          *pa0 = accA0[r] * arA; *pa1 = accA1[r] * arA;
          *pb0 = accB0[r] * arB; *pb1 = accB1[r] * arB;
        } else if (round > 0) {
          *pa0 += accA0[r] * arA; *pa1 += accA1[r] * arA;
          *pb0 += accB0[r] * arB; *pb1 += accB1[r] * arB;
        } else {
          const float lrA = __shfl(liA, qr, 64);
          const float lrB = __shfl(liB, qr, 64);
          const int rowA = qt * 64 + qr, rowB = qt * 64 + 32 + qr;
          og[(size_t)rowA * DIM + h * HD + q31] = f2b((accA0[r] * arA + *pa0) * lrA);
          og[(size_t)rowA * DIM + h * HD + 32 + q31] = f2b((accA1[r] * arA + *pa1) * lrA);
          og[(size_t)rowB * DIM + h * HD + q31] = f2b((accB0[r] * arB + *pb0) * lrB);
          og[(size_t)rowB * DIM + h * HD + 32 + q31] = f2b((accB1[r] * arB + *pb1) * lrB);
        }
      }
    }
    __syncthreads();
  }
}

// ---------- LayerNorm + per-modality affine + scatter (sums split-K partials) ----------
__global__ __launch_bounds__(256) void ln_scatter(const float* __restrict__ oa,
                                                  const float* __restrict__ ob,
                                                  const float* __restrict__ lnw,
                                                  const float* __restrict__ lnb,
                                                  const int* __restrict__ perm,
                                                  const int* __restrict__ cntp,
                                                  float* __restrict__ out) {
  const int i = blockIdx.x;
  const int tid = threadIdx.x, w = tid >> 6, l = tid & 63;
  const int mod = (i < cntp[0]) ? 0 : 1;
  float4 va = ((const float4*)(oa + (size_t)i * DIM))[tid];
  float4 vb = ((const float4*)(ob + (size_t)i * DIM))[tid];
  float4 v;
  v.x = va.x + vb.x; v.y = va.y + vb.y; v.z = va.z + vb.z; v.w = va.w + vb.w;
  float s = v.x + v.y + v.z + v.w;
  float ss = v.x * v.x + v.y * v.y + v.z * v.z + v.w * v.w;
  #pragma unroll
  for (int off = 1; off < 64; off <<= 1) {
    s += __shfl_xor(s, off, 64);
    ss += __shfl_xor(ss, off, 64);
  }
  __shared__ float rs4[4], rss4[4];
  if (l == 0) { rs4[w] = s; rss4[w] = ss; }
  __syncthreads();
  const float st = rs4[0] + rs4[1] + rs4[2] + rs4[3];
  const float sst = rss4[0] + rss4[1] + rss4[2] + rss4[3];
  const float mu = st * (1.f / DIM);
  const float var = sst * (1.f / DIM) - mu * mu;
  const float rstd = rsqrtf(var + 1e-5f);
  const int drow = perm[i];
  float4 g = ((const float4*)(lnw + (size_t)mod * DIM))[tid];
  float4 b = ((const float4*)(lnb + (size_t)mod * DIM))[tid];
  float4 rr;
  rr.x = (v.x - mu) * rstd * g.x + b.x;
  rr.y = (v.y - mu) * rstd * g.y + b.y;
  rr.z = (v.z - mu) * rstd * g.z + b.z;
  rr.w = (v.w - mu) * rstd * g.w + b.w;
  ((float4*)(out + (size_t)drow * DIM))[tid] = rr;
}

// ---------- launch ----------
extern "C" void kernel_launch(void* const* d_in, const int* in_sizes, int n_in,
                              void* d_out, int out_size, void* d_ws, size_t ws_size,
                              hipStream_t stream) {
  const float* x = (const float*)d_in[0];
  const void* masks = d_in[1];
  const float* wq = (const float*)d_in[3];
  const float* wk = (const float*)d_in[4];
  const float* wv = (const float*)d_in[5];
  const float* wo = (const float*)d_in[6];
  const float* lnw = (const float*)d_in[7];
  const float* lnb = (const float*)d_in[8];

  char* ws = (char*)d_ws;
  int* perm = (int*)(ws + OFF_PERM);
  int* cnt = (int*)(ws + OFF_CNT);
  u16* xpb = (u16*)(ws + OFF_XPB);
  u16* wT = (u16*)(ws + OFF_WT);
  u16* q = (u16*)(ws + OFF_Q);
  u16* k = (u16*)(ws + OFF_K);
  u16* vT = (u16*)(ws + OFF_VT);
  u16* at = (u16*)(ws + OFF_AT);
  float* o = (float*)(ws + OFF_O);
  float* o2 = (float*)(ws + OFF_O2);
  float* out = (float*)d_out;

  wcast_prep<<<dim3(32, 32, 9), dim3(32, 8), 0, stream>>>(wq, wk, wv, wo, wT, masks, perm, cnt);
  gather_cast<<<N_TOK, 256, 0, stream>>>(x, perm, xpb);
  gemm_qkv<<<dim3(8, 32, 3), 256, 0, stream>>>(xpb, wT, QSCALE, q, k, vT, cnt);
  attn_fwd<<<512, 256, 0, stream>>>(q, k, vT, at);
  gemm_out<<<dim3(16, 32, 2), 256, 0, stream>>>(at, wT, o, o2, cnt);
  ln_scatter<<<N_TOK, 256, 0, stream>>>(o, o2, lnw, lnb, perm, cnt, out);
}